// Round 10
// baseline (193.715 us; speedup 1.0000x reference)
//
#include <hip/hip_runtime.h>
#include <hip/hip_fp16.h>

typedef _Float16 f16;
typedef _Float16 f16x8 __attribute__((ext_vector_type(8)));
typedef _Float16 f16x2v __attribute__((ext_vector_type(2)));
typedef __fp16 h16x2 __attribute__((ext_vector_type(2)));
typedef float f32x4 __attribute__((ext_vector_type(4)));
typedef float f32x16 __attribute__((ext_vector_type(16)));

#define LOG2E 1.4426950408889634f
#define NSL 0.2f

// ---------------- Kernel A: xcvt + swizzled weight transposes + M2e init ----------------
__global__ __launch_bounds__(256) void k_a(const float* __restrict__ x,
                                           f16* __restrict__ xh2,
                                           const float* __restrict__ W,
                                           f16* __restrict__ Wht2,
                                           const float* __restrict__ Wr,
                                           f16* __restrict__ Wrt2,
                                           unsigned int* __restrict__ M2e) {
    __shared__ float tile[32][33];
    int bx = blockIdx.x;
    int tid = threadIdx.x;
    if (bx == 0 && tid < 8) M2e[tid] = 0x007FFFFFu;  // enc(-inf)
    if (bx < 512) {
        int id = bx * 256 + tid;   // 131072
        int row = id & 4095, kt = id >> 12;
        const float4* xs = (const float4*)(x + (size_t)row * 512 + kt * 16);
        float4 u0 = xs[0], u1 = xs[1], u2 = xs[2], u3 = xs[3];
        union { int4 a[2]; h16x2 p[8]; } px;
        px.p[0] = __builtin_amdgcn_cvt_pkrtz(u0.x, u0.y);
        px.p[1] = __builtin_amdgcn_cvt_pkrtz(u0.z, u0.w);
        px.p[2] = __builtin_amdgcn_cvt_pkrtz(u1.x, u1.y);
        px.p[3] = __builtin_amdgcn_cvt_pkrtz(u1.z, u1.w);
        px.p[4] = __builtin_amdgcn_cvt_pkrtz(u2.x, u2.y);
        px.p[5] = __builtin_amdgcn_cvt_pkrtz(u2.z, u2.w);
        px.p[6] = __builtin_amdgcn_cvt_pkrtz(u3.x, u3.y);
        px.p[7] = __builtin_amdgcn_cvt_pkrtz(u3.z, u3.w);
        int4* d = (int4*)(xh2 + ((size_t)kt * 4096 + row) * 16);
        d[0] = px.a[0]; d[1] = px.a[1];
    } else {
        const float* in; f16* out; int C, S, bxx, byy;
        if (bx < 1024) { int id = bx - 512;  in = W;  out = Wht2; C = 128;  S = 128;  bxx = id & 3;  byy = id >> 2; }
        else           { int id = bx - 1024; in = Wr; out = Wrt2; C = 1024; S = 1024; bxx = id & 31; byy = id >> 5; }
        int tx = tid & 31, ty = tid >> 5;
        int c0 = bxx * 32, r0 = byy * 32;
        for (int rr = ty; rr < 32; rr += 8)
            tile[rr][tx] = in[(r0 + rr) * C + c0 + tx];
        __syncthreads();
        for (int rr = ty; rr < 32; rr += 8) {
            int m = r0 + tx, f = c0 + rr;
            out[(size_t)((m >> 4) * S + f) * 16 + (m & 15)] = (f16)tile[tx][rr];
        }
    }
}

// ---------------- Kernel B (fused): gemm_h (blocks 0..1023) + graph bitmask (1024..3071) ----------------
__global__ __launch_bounds__(256, 4) void k_b(const f16* __restrict__ xh2,
                                              const f16* __restrict__ Wht2,
                                              f16* __restrict__ hbT2,
                                              const float* __restrict__ wi,
                                              const float* __restrict__ wj,
                                              float* __restrict__ a2,
                                              float* __restrict__ b2,
                                              unsigned int* __restrict__ M2e,
                                              const int* __restrict__ graph,
                                              unsigned int* __restrict__ maskJ) {
    __shared__ float swi[128], swj[128];
    __shared__ float pwa[4][32], pwb[4][32];
    int bx = blockIdx.x;
    int tid = threadIdx.x;
    int w = tid >> 6, lane = tid & 63;

    if (bx >= 1024) {
        // ---- mask part: one thread per output word, 32-deep independent loads ----
        int e = (bx - 1024) * 256 + tid;       // 0..524287 = jw*4096 + i
        int jw = e >> 12, ii = e & 4095;
        const int* gp = graph + (size_t)(jw << 5) * 4096 + ii;
        int gv[32];
        #pragma unroll
        for (int k = 0; k < 32; k++) gv[k] = gp[(size_t)k * 4096];
        unsigned word = 0;
        #pragma unroll
        for (int k = 0; k < 32; k++) word |= (gv[k] > 0) ? (1u << k) : 0u;
        maskJ[e] = word;
        return;
    }

    // ---- gemm part ----
    int h = bx & 7, jb = bx >> 3;        // 128 j-tiles of 32
    int j0 = jb * 32;
    int ln = lane & 15, q = lane >> 4;
    if (tid < 128) { swi[tid] = wi[h * 128 + tid]; swj[tid] = wj[h * 128 + tid]; }
    __syncthreads();

    int ko = (q & 1) * 8;
    const f16* pa = Wht2 + ((size_t)(h * 512) * 8 + (size_t)(q >> 1) * 128 + w * 32 + ln) * 16 + ko;
    const f16* pb = xh2 + ((size_t)(q >> 1) * 4096 + j0 + ln) * 16 + ko;

    f32x4 acc00 = {}, acc01 = {}, acc10 = {}, acc11 = {};

    f16x8 ra0 = *(const f16x8*)(pa);
    f16x8 ra1 = *(const f16x8*)(pa + 256);
    f16x8 rb0 = *(const f16x8*)(pb);
    f16x8 rb1 = *(const f16x8*)(pb + 256);

    for (int kk = 0; kk < 8; kk++) {
        f16x8 sa0 = *(const f16x8*)(pa + 4096);
        f16x8 sa1 = *(const f16x8*)(pa + 4096 + 256);
        f16x8 sb0 = *(const f16x8*)(pb + 131072);
        f16x8 sb1 = *(const f16x8*)(pb + 131072 + 256);
        acc00 = __builtin_amdgcn_mfma_f32_16x16x32_f16(ra0, rb0, acc00, 0, 0, 0);
        acc01 = __builtin_amdgcn_mfma_f32_16x16x32_f16(ra0, rb1, acc01, 0, 0, 0);
        acc10 = __builtin_amdgcn_mfma_f32_16x16x32_f16(ra1, rb0, acc10, 0, 0, 0);
        acc11 = __builtin_amdgcn_mfma_f32_16x16x32_f16(ra1, rb1, acc11, 0, 0, 0);
        pa += 8192; pb += 262144;
        ra0 = *(const f16x8*)(pa);
        ra1 = *(const f16x8*)(pa + 256);
        rb0 = *(const f16x8*)(pb);
        rb1 = *(const f16x8*)(pb + 256);
        acc00 = __builtin_amdgcn_mfma_f32_16x16x32_f16(sa0, sb0, acc00, 0, 0, 0);
        acc01 = __builtin_amdgcn_mfma_f32_16x16x32_f16(sa0, sb1, acc01, 0, 0, 0);
        acc10 = __builtin_amdgcn_mfma_f32_16x16x32_f16(sa1, sb0, acc10, 0, 0, 0);
        acc11 = __builtin_amdgcn_mfma_f32_16x16x32_f16(sa1, sb1, acc11, 0, 0, 0);
    }

    size_t hb = (size_t)h * 524288 + (size_t)(j0 >> 4) * 2048;
    #pragma unroll
    for (int r = 0; r < 4; r++) {
        int f0 = w * 32 + q * 4 + r;
        hbT2[hb + f0 * 16 + ln]                 = (f16)acc00[r];
        hbT2[hb + 2048 + f0 * 16 + ln]          = (f16)acc01[r];
        hbT2[hb + (f0 + 16) * 16 + ln]          = (f16)acc10[r];
        hbT2[hb + 2048 + (f0 + 16) * 16 + ln]   = (f16)acc11[r];
    }

    float pa0 = 0.f, pb0 = 0.f, pa1 = 0.f, pb1 = 0.f;
    #pragma unroll
    for (int r = 0; r < 4; r++) {
        int f0 = w * 32 + q * 4 + r;
        float w0 = swi[f0], jv0 = swj[f0];
        float w1 = swi[f0 + 16], jv1 = swj[f0 + 16];
        pa0 += acc00[r] * w0 + acc10[r] * w1;
        pb0 += acc00[r] * jv0 + acc10[r] * jv1;
        pa1 += acc01[r] * w0 + acc11[r] * w1;
        pb1 += acc01[r] * jv0 + acc11[r] * jv1;
    }
    pa0 += __shfl_xor(pa0, 16); pa0 += __shfl_xor(pa0, 32);
    pb0 += __shfl_xor(pb0, 16); pb0 += __shfl_xor(pb0, 32);
    pa1 += __shfl_xor(pa1, 16); pa1 += __shfl_xor(pa1, 32);
    pb1 += __shfl_xor(pb1, 16); pb1 += __shfl_xor(pb1, 32);
    if (lane < 16) {
        pwa[w][ln] = pa0;      pwb[w][ln] = pb0;
        pwa[w][16 + ln] = pa1; pwb[w][16 + ln] = pb1;
    }
    __syncthreads();
    if (tid < 32) {
        int jj = tid;
        float pav = (pwa[0][jj] + pwa[1][jj]) + (pwa[2][jj] + pwa[3][jj]);
        float pbv = (pwb[0][jj] + pwb[1][jj]) + (pwb[2][jj] + pwb[3][jj]);
        a2[h * 4096 + j0 + jj] = pav * LOG2E;
        float bb = pbv * LOG2E;
        b2[h * 4096 + j0 + jj] = bb;
        float m = bb;
        m = fmaxf(m, __shfl_xor(m, 1, 32));
        m = fmaxf(m, __shfl_xor(m, 2, 32));
        m = fmaxf(m, __shfl_xor(m, 4, 32));
        m = fmaxf(m, __shfl_xor(m, 8, 32));
        m = fmaxf(m, __shfl_xor(m, 16, 32));
        if (jj == 0) {
            unsigned u = __float_as_uint(m);
            unsigned enc = (u & 0x80000000u) ? ~u : (u | 0x80000000u);
            atomicMax(&M2e[h], enc);
        }
    }
}

// ---------------- Kernel 6 helpers ----------------
#define PGEN2(af, m8, qv, qw, A1, A2, DS)                                            \
    {                                                                                \
        union { int4 i4; unsigned u[4]; } uv, uw;                                    \
        uv.i4 = (qv); uw.i4 = (qw);                                                  \
        f16x2v dl = {(_Float16)0, (_Float16)0};                                      \
        _Pragma("unroll")                                                            \
        for (int p = 0; p < 4; p++) {                                                \
            union { unsigned u; f16x2v v; } b1, b2x, mm;                             \
            b1.u = uv.u[p]; b2x.u = uw.u[p];                                         \
            f16x2v pr1 = (A1) * b1.v;                                                \
            f16x2v pr2 = (A2) * b2x.v;                                               \
            mm.v = __builtin_elementwise_max(pr1, pr2);                              \
            int mlo = -(int)(((m8) >> (2 * p)) & 1u);                                \
            int mhi = -(int)(((m8) >> (2 * p + 1)) & 1u);                            \
            unsigned comb = ((unsigned)mlo & 0xFFFFu) | ((unsigned)mhi & 0xFFFF0000u);\
            mm.u &= comb;                                                            \
            af.u[p] = mm.u;                                                          \
            dl += mm.v;                                                              \
        }                                                                            \
        DS += (float)dl.x + (float)dl.y;                                             \
    }

// ---------------- Kernel 6: main — producer/consumer P-in-LDS: per 64-j chunk, all 8
// waves PGEN the 64x64 P-tile into LDS (dbuf), then each wave MFMAs its 32-row x 32-f
// slice. acc/thread 128->16, xred epilogue eliminated, occupancy 2x512-thr blocks/CU ----------------
__global__ __launch_bounds__(512, 4) void k_main(const f16* __restrict__ xh2,
                                                 const f16* __restrict__ hbT2,
                                                 const f16* __restrict__ Wrt2,
                                                 const unsigned int* __restrict__ maskJ,
                                                 const float* __restrict__ a2,
                                                 const float* __restrict__ b2,
                                                 const unsigned int* __restrict__ M2e,
                                                 const float* __restrict__ bias,
                                                 float* __restrict__ out) {
    // [0,8192) P buf0 | [8192,16384) P buf1 | [16384,24576) Bv | [24576,32768) Bw
    // [32768,34816) dred[8][64] | [34816,35072) rsum[64]
    __shared__ char smem[35328];
    char* pb0 = smem;
    char* pb1 = smem + 8192;
    unsigned int* bvlds = (unsigned int*)(smem + 16384);
    unsigned int* bwlds = (unsigned int*)(smem + 24576);
    float* dred = (float*)(smem + 32768);
    float* rsum = (float*)(smem + 34816);

    int bx = blockIdx.x;
    int h = bx & 7, it = bx >> 3;         // 64 i-tiles of 64 rows
    int i0 = it * 64;
    int tid = threadIdx.x;
    int w = tid >> 6, lane = tid & 63;
    int l31 = lane & 31, half = lane >> 5;

    // producer role: row + j-octet (8 j's per thread per chunk)
    int prow = tid & 63;
    int poct = w;                          // 0..7 (chunk = 64 j = 8 octets)
    int mshift = (poct & 3) * 8;
    // consumer role: f-slice + row-half
    int fs = (w & 3) * 32;
    int rh = (w >> 2) * 32;

    unsigned enc = M2e[h];
    unsigned um = (enc & 0x80000000u) ? (enc & 0x7FFFFFFFu) : ~enc;
    float M2 = __uint_as_float(um);

    // ---- build Bv/Bw tables ----
    {
        const float2* bsrc = (const float2*)(b2 + h * 4096);
        #pragma unroll
        for (int c = 0; c < 4; c++) {
            int p = tid + c * 512;                 // 2048 j-pairs
            float2 tb = bsrc[p];
            float t0 = tb.x - M2, t1 = tb.y - M2;
            union { h16x2 pp; unsigned ii; } k1, k2;
            k1.pp = __builtin_amdgcn_cvt_pkrtz(exp2f(t0), exp2f(t1));
            k2.pp = __builtin_amdgcn_cvt_pkrtz(exp2f(NSL * t0), exp2f(NSL * t1));
            bvlds[p] = k1.ii;
            bwlds[p] = k2.ii;
        }
    }

    // ---- per-row A factors for the producer row ----
    float av = a2[h * 4096 + i0 + prow];
    float uu = av + M2;
    float m2v = fmaxf(uu, NSL * uu);
    union { h16x2 pp; f16x2v v; } apk;
    apk.pp = __builtin_amdgcn_cvt_pkrtz(exp2f(uu - m2v), exp2f(NSL * uu - m2v));
    f16x2v Ap1 = {apk.v.x, apk.v.x};
    f16x2v Ap2 = {apk.v.y, apk.v.y};
    float dsum = 0.f;

    f32x16 acc = {};

    int wroff = poct * 1024 + prow * 16;   // P write slot (bytes)
    // hbT2 B base for this wave's f-slice (f16 units); frag for j16-tile jt at +jt*2048
    const f16* bb = hbT2 + (size_t)h * 524288 + (size_t)(fs + l31) * 16 + half * 8;
    // mask word ptr: chunk c, this thread's word at mpp[c*8192]
    const unsigned int* mpp = maskJ + (size_t)(poct >> 2) * 4096 + i0 + prow;

    __syncthreads();

#define PFB(C, B0, B1, B2, B3)                                           \
    B0 = *(const f16x8*)(bb + (size_t)((C) * 4 + 0) * 2048);             \
    B1 = *(const f16x8*)(bb + (size_t)((C) * 4 + 1) * 2048);             \
    B2 = *(const f16x8*)(bb + (size_t)((C) * 4 + 2) * 2048);             \
    B3 = *(const f16x8*)(bb + (size_t)((C) * 4 + 3) * 2048);

#define PGC(C, PB, MW)                                                   \
    {                                                                    \
        int4 qv = *(const int4*)(bvlds + (C) * 32 + poct * 4);           \
        int4 qw = *(const int4*)(bwlds + (C) * 32 + poct * 4);           \
        union { f16x8 v; unsigned u[4]; int4 i4; } af;                   \
        unsigned m8v = (MW) >> mshift;                                   \
        PGEN2(af, m8v, qv, qw, Ap1, Ap2, dsum);                          \
        *(int4*)((PB) + wroff) = af.i4;                                  \
    }

#define MMC(PB, B0, B1, B2, B3)                                          \
    {                                                                    \
        const f16* pr = (const f16*)(PB) + (size_t)(rh + l31) * 8;       \
        f16x8 a0 = *(const f16x8*)(pr + (0 + half) * 512);               \
        f16x8 a1 = *(const f16x8*)(pr + (2 + half) * 512);               \
        f16x8 a2f = *(const f16x8*)(pr + (4 + half) * 512);              \
        f16x8 a3 = *(const f16x8*)(pr + (6 + half) * 512);               \
        __builtin_amdgcn_s_setprio(1);                                   \
        acc = __builtin_amdgcn_mfma_f32_32x32x16_f16(a0, B0, acc, 0, 0, 0); \
        acc = __builtin_amdgcn_mfma_f32_32x32x16_f16(a1, B1, acc, 0, 0, 0); \
        acc = __builtin_amdgcn_mfma_f32_32x32x16_f16(a2f, B2, acc, 0, 0, 0);\
        acc = __builtin_amdgcn_mfma_f32_32x32x16_f16(a3, B3, acc, 0, 0, 0); \
        __builtin_amdgcn_s_setprio(0);                                   \
    }

    f16x8 bA0, bA1, bA2, bA3, bB0, bB1, bB2, bB3;
    PFB(0, bA0, bA1, bA2, bA3)
    PFB(1, bB0, bB1, bB2, bB3)
    unsigned mwE = mpp[0];
    unsigned mwO = mpp[8192];
    PGC(0, pb0, mwE)
    mwE = mpp[2 * 8192];
    __syncthreads();

    #pragma unroll 1
    for (int c = 0; c < 62; c += 2) {
        PGC(c + 1, pb1, mwO)
        mwO = mpp[(size_t)(c + 3) * 8192];
        MMC(pb0, bA0, bA1, bA2, bA3)
        PFB(c + 2, bA0, bA1, bA2, bA3)
        __syncthreads();
        PGC(c + 2, pb0, mwE)
        mwE = mpp[(size_t)(c + 4) * 8192];
        MMC(pb1, bB0, bB1, bB2, bB3)
        PFB(c + 3, bB0, bB1, bB2, bB3)
        __syncthreads();
    }
    // tail: chunk 63 PGEN; chunks 62,63 MFMA
    PGC(63, pb1, mwO)
    MMC(pb0, bA0, bA1, bA2, bA3)
    __syncthreads();
    MMC(pb1, bB0, bB1, bB2, bB3)

    // ---- denominator: dsum per (row, octet) -> row sums ----
    dred[poct * 64 + prow] = dsum;
    __syncthreads();
    if (tid < 64) {
        float s = 0.f;
        #pragma unroll
        for (int o = 0; o < 8; o++) s += dred[o * 64 + tid];
        rsum[tid] = 1.0f / s;
    }
    __syncthreads();
    {
        #pragma unroll
        for (int r = 0; r < 16; r++) {
            int rowl = (r & 3) + 8 * (r >> 2) + 4 * half + rh;
            acc[r] *= rsum[rowl];
        }
    }

    // ---- residual: this wave's 32 rows x 32 f over full K=512 ----
    {
        #pragma unroll 4
        for (int kt = 0; kt < 32; kt++) {
            f16x8 ax = *(const f16x8*)(xh2 + ((size_t)kt * 4096 + i0 + rh + l31) * 16 + half * 8);
            f16x8 wb = *(const f16x8*)(Wrt2 + ((size_t)kt * 1024 + h * 128 + fs + l31) * 16 + half * 8);
            acc = __builtin_amdgcn_mfma_f32_32x32x16_f16(ax, wb, acc, 0, 0, 0);
        }
    }

    // ---- epilogue: each wave owns its output slice — direct store ----
    {
        int col = h * 128 + fs + l31;
        float bv = bias[col];
        #pragma unroll
        for (int r = 0; r < 16; r++) {
            int row = i0 + rh + (r & 3) + 8 * (r >> 2) + 4 * half;
            out[(size_t)row * 1024 + col] = acc[r] + bv;
        }
    }
#undef PFB
#undef PGC
#undef MMC
}

extern "C" void kernel_launch(void* const* d_in, const int* in_sizes, int n_in,
                              void* d_out, int out_size, void* d_ws, size_t ws_size,
                              hipStream_t stream) {
    (void)in_sizes; (void)n_in; (void)out_size; (void)ws_size;
    const float* x     = (const float*)d_in[0];
    const int*   graph = (const int*)d_in[1];
    const float* W     = (const float*)d_in[2];
    const float* wi    = (const float*)d_in[3];
    const float* wj    = (const float*)d_in[4];
    const float* Wr    = (const float*)d_in[5];
    const float* bias  = (const float*)d_in[6];
    float* out = (float*)d_out;

    char* ws = (char*)d_ws;
    unsigned int* maskJ = (unsigned int*)ws;              // 2 MB  [128 jw][4096 i]
    f16* hbT2  = (f16*)(ws + (2u << 20));                 // 8 MB  [8][(j>>4)*128+f][j&15]
    f16* Wht2  = (f16*)(ws + (10u << 20));                // 1 MB  swizzled
    f16* Wrt2  = (f16*)(ws + (11u << 20));                // 1 MB  swizzled
    f16* xh2   = (f16*)(ws + (12u << 20));                // 4 MB  [32][4096][16] swizzled
    float* a2    = (float*)(ws + (16u << 20));            // 128 KB
    float* b2    = a2 + 8 * 4096;                         // 128 KB
    unsigned int* M2e = (unsigned int*)(b2 + 8 * 4096);   // 32 B

    hipLaunchKernelGGL(k_a, dim3(1536), dim3(256), 0, stream, x, xh2, W, Wht2, Wr, Wrt2, M2e);
    hipLaunchKernelGGL(k_b, dim3(3072), dim3(256), 0, stream, xh2, Wht2, hbT2,
                       wi, wj, a2, b2, M2e, graph, maskJ);
    hipLaunchKernelGGL(k_main, dim3(512), dim3(512), 0, stream, xh2, hbT2, Wrt2, maskJ,
                       a2, b2, M2e, bias, out);
}

// Round 11
// 179.478 us; speedup vs baseline: 1.0793x; 1.0793x over previous
//
#include <hip/hip_runtime.h>
#include <hip/hip_fp16.h>

typedef _Float16 f16;
typedef _Float16 f16x8 __attribute__((ext_vector_type(8)));
typedef _Float16 f16x2v __attribute__((ext_vector_type(2)));
typedef __fp16 h16x2 __attribute__((ext_vector_type(2)));
typedef float f32x4 __attribute__((ext_vector_type(4)));
typedef float f32x16 __attribute__((ext_vector_type(16)));

#define LOG2E 1.4426950408889634f
#define NSL 0.2f

// ---------------- Kernel A: xcvt + swizzled weight transposes + M2e init ----------------
__global__ __launch_bounds__(256) void k_a(const float* __restrict__ x,
                                           f16* __restrict__ xh2,
                                           const float* __restrict__ W,
                                           f16* __restrict__ Wht2,
                                           const float* __restrict__ Wr,
                                           f16* __restrict__ Wrt2,
                                           unsigned int* __restrict__ M2e) {
    __shared__ float tile[32][33];
    int bx = blockIdx.x;
    int tid = threadIdx.x;
    if (bx == 0 && tid < 8) M2e[tid] = 0x007FFFFFu;  // enc(-inf)
    if (bx < 512) {
        int id = bx * 256 + tid;   // 131072
        int row = id & 4095, kt = id >> 12;
        const float4* xs = (const float4*)(x + (size_t)row * 512 + kt * 16);
        float4 u0 = xs[0], u1 = xs[1], u2 = xs[2], u3 = xs[3];
        union { int4 a[2]; h16x2 p[8]; } px;
        px.p[0] = __builtin_amdgcn_cvt_pkrtz(u0.x, u0.y);
        px.p[1] = __builtin_amdgcn_cvt_pkrtz(u0.z, u0.w);
        px.p[2] = __builtin_amdgcn_cvt_pkrtz(u1.x, u1.y);
        px.p[3] = __builtin_amdgcn_cvt_pkrtz(u1.z, u1.w);
        px.p[4] = __builtin_amdgcn_cvt_pkrtz(u2.x, u2.y);
        px.p[5] = __builtin_amdgcn_cvt_pkrtz(u2.z, u2.w);
        px.p[6] = __builtin_amdgcn_cvt_pkrtz(u3.x, u3.y);
        px.p[7] = __builtin_amdgcn_cvt_pkrtz(u3.z, u3.w);
        int4* d = (int4*)(xh2 + ((size_t)kt * 4096 + row) * 16);
        d[0] = px.a[0]; d[1] = px.a[1];
    } else {
        const float* in; f16* out; int C, S, bxx, byy;
        if (bx < 1024) { int id = bx - 512;  in = W;  out = Wht2; C = 128;  S = 128;  bxx = id & 3;  byy = id >> 2; }
        else           { int id = bx - 1024; in = Wr; out = Wrt2; C = 1024; S = 1024; bxx = id & 31; byy = id >> 5; }
        int tx = tid & 31, ty = tid >> 5;
        int c0 = bxx * 32, r0 = byy * 32;
        for (int rr = ty; rr < 32; rr += 8)
            tile[rr][tx] = in[(r0 + rr) * C + c0 + tx];
        __syncthreads();
        for (int rr = ty; rr < 32; rr += 8) {
            int m = r0 + tx, f = c0 + rr;
            out[(size_t)((m >> 4) * S + f) * 16 + (m & 15)] = (f16)tile[tx][rr];
        }
    }
}

// ---------------- Kernel B (fused): gemm_h (blocks 0..1023) + graph bitmask (1024..3071) ----------------
// Mask build: ballot-free, 32 independent dword loads per thread -> deep MLP, HBM-BW-bound;
// overlaps the latency-bound gemm on the same CUs.
__global__ __launch_bounds__(256, 4) void k_b(const f16* __restrict__ xh2,
                                              const f16* __restrict__ Wht2,
                                              f16* __restrict__ hbT2,
                                              const float* __restrict__ wi,
                                              const float* __restrict__ wj,
                                              float* __restrict__ a2,
                                              float* __restrict__ b2,
                                              unsigned int* __restrict__ M2e,
                                              const int* __restrict__ graph,
                                              unsigned int* __restrict__ maskJ) {
    __shared__ float swi[128], swj[128];
    __shared__ float pwa[4][32], pwb[4][32];
    int bx = blockIdx.x;
    int tid = threadIdx.x;
    int w = tid >> 6, lane = tid & 63;

    if (bx >= 1024) {
        // ---- mask part: one thread per output word, 32-deep independent loads ----
        int e = (bx - 1024) * 256 + tid;       // 0..524287 = jw*4096 + i
        int jw = e >> 12, ii = e & 4095;
        const int* gp = graph + (size_t)(jw << 5) * 4096 + ii;
        int gv[32];
        #pragma unroll
        for (int k = 0; k < 32; k++) gv[k] = gp[(size_t)k * 4096];
        unsigned word = 0;
        #pragma unroll
        for (int k = 0; k < 32; k++) word |= (gv[k] > 0) ? (1u << k) : 0u;
        maskJ[e] = word;
        return;
    }

    // ---- gemm part ----
    int h = bx & 7, jb = bx >> 3;        // 128 j-tiles of 32
    int j0 = jb * 32;
    int ln = lane & 15, q = lane >> 4;
    if (tid < 128) { swi[tid] = wi[h * 128 + tid]; swj[tid] = wj[h * 128 + tid]; }
    __syncthreads();

    int ko = (q & 1) * 8;
    const f16* pa = Wht2 + ((size_t)(h * 512) * 8 + (size_t)(q >> 1) * 128 + w * 32 + ln) * 16 + ko;
    const f16* pb = xh2 + ((size_t)(q >> 1) * 4096 + j0 + ln) * 16 + ko;

    f32x4 acc00 = {}, acc01 = {}, acc10 = {}, acc11 = {};

    f16x8 ra0 = *(const f16x8*)(pa);
    f16x8 ra1 = *(const f16x8*)(pa + 256);
    f16x8 rb0 = *(const f16x8*)(pb);
    f16x8 rb1 = *(const f16x8*)(pb + 256);

    for (int kk = 0; kk < 8; kk++) {
        f16x8 sa0 = *(const f16x8*)(pa + 4096);
        f16x8 sa1 = *(const f16x8*)(pa + 4096 + 256);
        f16x8 sb0 = *(const f16x8*)(pb + 131072);
        f16x8 sb1 = *(const f16x8*)(pb + 131072 + 256);
        acc00 = __builtin_amdgcn_mfma_f32_16x16x32_f16(ra0, rb0, acc00, 0, 0, 0);
        acc01 = __builtin_amdgcn_mfma_f32_16x16x32_f16(ra0, rb1, acc01, 0, 0, 0);
        acc10 = __builtin_amdgcn_mfma_f32_16x16x32_f16(ra1, rb0, acc10, 0, 0, 0);
        acc11 = __builtin_amdgcn_mfma_f32_16x16x32_f16(ra1, rb1, acc11, 0, 0, 0);
        pa += 8192; pb += 262144;
        ra0 = *(const f16x8*)(pa);
        ra1 = *(const f16x8*)(pa + 256);
        rb0 = *(const f16x8*)(pb);
        rb1 = *(const f16x8*)(pb + 256);
        acc00 = __builtin_amdgcn_mfma_f32_16x16x32_f16(sa0, sb0, acc00, 0, 0, 0);
        acc01 = __builtin_amdgcn_mfma_f32_16x16x32_f16(sa0, sb1, acc01, 0, 0, 0);
        acc10 = __builtin_amdgcn_mfma_f32_16x16x32_f16(sa1, sb0, acc10, 0, 0, 0);
        acc11 = __builtin_amdgcn_mfma_f32_16x16x32_f16(sa1, sb1, acc11, 0, 0, 0);
    }

    size_t hb = (size_t)h * 524288 + (size_t)(j0 >> 4) * 2048;
    #pragma unroll
    for (int r = 0; r < 4; r++) {
        int f0 = w * 32 + q * 4 + r;
        hbT2[hb + f0 * 16 + ln]                 = (f16)acc00[r];
        hbT2[hb + 2048 + f0 * 16 + ln]          = (f16)acc01[r];
        hbT2[hb + (f0 + 16) * 16 + ln]          = (f16)acc10[r];
        hbT2[hb + 2048 + (f0 + 16) * 16 + ln]   = (f16)acc11[r];
    }

    float pa0 = 0.f, pb0 = 0.f, pa1 = 0.f, pb1 = 0.f;
    #pragma unroll
    for (int r = 0; r < 4; r++) {
        int f0 = w * 32 + q * 4 + r;
        float w0 = swi[f0], jv0 = swj[f0];
        float w1 = swi[f0 + 16], jv1 = swj[f0 + 16];
        pa0 += acc00[r] * w0 + acc10[r] * w1;
        pb0 += acc00[r] * jv0 + acc10[r] * jv1;
        pa1 += acc01[r] * w0 + acc11[r] * w1;
        pb1 += acc01[r] * jv0 + acc11[r] * jv1;
    }
    pa0 += __shfl_xor(pa0, 16); pa0 += __shfl_xor(pa0, 32);
    pb0 += __shfl_xor(pb0, 16); pb0 += __shfl_xor(pb0, 32);
    pa1 += __shfl_xor(pa1, 16); pa1 += __shfl_xor(pa1, 32);
    pb1 += __shfl_xor(pb1, 16); pb1 += __shfl_xor(pb1, 32);
    if (lane < 16) {
        pwa[w][ln] = pa0;      pwb[w][ln] = pb0;
        pwa[w][16 + ln] = pa1; pwb[w][16 + ln] = pb1;
    }
    __syncthreads();
    if (tid < 32) {
        int jj = tid;
        float pav = (pwa[0][jj] + pwa[1][jj]) + (pwa[2][jj] + pwa[3][jj]);
        float pbv = (pwb[0][jj] + pwb[1][jj]) + (pwb[2][jj] + pwb[3][jj]);
        a2[h * 4096 + j0 + jj] = pav * LOG2E;
        float bb = pbv * LOG2E;
        b2[h * 4096 + j0 + jj] = bb;
        float m = bb;
        m = fmaxf(m, __shfl_xor(m, 1, 32));
        m = fmaxf(m, __shfl_xor(m, 2, 32));
        m = fmaxf(m, __shfl_xor(m, 4, 32));
        m = fmaxf(m, __shfl_xor(m, 8, 32));
        m = fmaxf(m, __shfl_xor(m, 16, 32));
        if (jj == 0) {
            unsigned u = __float_as_uint(m);
            unsigned enc = (u & 0x80000000u) ? ~u : (u | 0x80000000u);
            atomicMax(&M2e[h], enc);
        }
    }
}

// ---------------- Kernel 6 helpers ----------------
#define PGEN2(af, m8, qv, qw, A1, A2, DS)                                            \
    {                                                                                \
        union { int4 i4; unsigned u[4]; } uv, uw;                                    \
        uv.i4 = (qv); uw.i4 = (qw);                                                  \
        f16x2v dl = {(_Float16)0, (_Float16)0};                                      \
        _Pragma("unroll")                                                            \
        for (int p = 0; p < 4; p++) {                                                \
            union { unsigned u; f16x2v v; } b1, b2x, mm;                             \
            b1.u = uv.u[p]; b2x.u = uw.u[p];                                         \
            f16x2v pr1 = (A1) * b1.v;                                                \
            f16x2v pr2 = (A2) * b2x.v;                                               \
            mm.v = __builtin_elementwise_max(pr1, pr2);                              \
            int mlo = -(int)(((m8) >> (2 * p)) & 1u);                                \
            int mhi = -(int)(((m8) >> (2 * p + 1)) & 1u);                            \
            unsigned comb = ((unsigned)mlo & 0xFFFFu) | ((unsigned)mhi & 0xFFFF0000u);\
            mm.u &= comb;                                                            \
            af.u[p] = mm.u;                                                          \
            dl += mm.v;                                                              \
        }                                                                            \
        DS += (float)dl.x + (float)dl.y;                                             \
    }

#define PUTACC(dp, off, accv)                                                    \
    {                                                                            \
        union { f32x16 v; f32x4 q[4]; } t; t.v = (accv);                         \
        *(f32x4*)((dp) + (off))      = t.q[0];                                   \
        *(f32x4*)((dp) + (off) + 4)  = t.q[1];                                   \
        *(f32x4*)((dp) + (off) + 8)  = t.q[2];                                   \
        *(f32x4*)((dp) + (off) + 12) = t.q[3];                                   \
    }

#define ADDACC(dp, off, accv)                                                    \
    {                                                                            \
        union { f32x16 v; f32x4 q[4]; } t; t.v = (accv);                         \
        t.q[0] += *(const f32x4*)((dp) + (off));                                 \
        t.q[1] += *(const f32x4*)((dp) + (off) + 4);                             \
        t.q[2] += *(const f32x4*)((dp) + (off) + 8);                             \
        t.q[3] += *(const f32x4*)((dp) + (off) + 12);                            \
        (accv) = t.v;                                                            \
    }

// ---------------- Kernel 6: main — best measured (56.4 µs): 64-row i-tiles; register
// frag dbuf with compiler scheduling; mask read direct from global (L2) with 1-tp
// prefetch; s_setprio around MFMA clusters; 2 waves/SIMD.
// NOTE (plateau ledger): deeper reg pipeline -> spill (R3); LDS ring + counted vmcnt ->
// serialization (R7); P-in-LDS producer/consumer -> barrier lockstep (R10). This
// structure is the verified optimum of the four. ----------------
__global__ __launch_bounds__(256, 2) void k_main(const f16* __restrict__ xh2,
                                                 const f16* __restrict__ hbT2,
                                                 const f16* __restrict__ Wrt2,
                                                 const unsigned int* __restrict__ maskJ,
                                                 const float* __restrict__ a2,
                                                 const float* __restrict__ b2,
                                                 const unsigned int* __restrict__ M2e,
                                                 const float* __restrict__ bias,
                                                 float* __restrict__ out) {
    // loop phase: [0,8192) Bv | [8192,16384) Bw  (+16B tail overread pad inside region)
    // post-loop:  [0,34816) xred (aliases Bv/Bw, separated by __syncthreads)
    __shared__ char smem[35328];
    __shared__ float dred[256];           // [wave][64 rows]

    unsigned int* bvlds = (unsigned int*)smem;
    unsigned int* bwlds = (unsigned int*)(smem + 8192);

    int bx = blockIdx.x;
    int h = bx & 7, it = bx >> 3;         // 64 i-tiles of 64 rows
    int i0 = it * 64;
    int tid = threadIdx.x;
    int w = tid >> 6, lane = tid & 63;
    int l31 = lane & 31, half = lane >> 5;
    int i = i0 + l31;

    unsigned enc = M2e[h];
    unsigned um = (enc & 0x80000000u) ? (enc & 0x7FFFFFFFu) : ~enc;
    float M2 = __uint_as_float(um);

    // ---- build Bv/Bw tables in LDS from b2 ----
    {
        const float2* bsrc = (const float2*)(b2 + h * 4096);
        #pragma unroll
        for (int c = 0; c < 8; c++) {
            int p = tid + c * 256;                 // 2048 j-pairs
            float2 tb = bsrc[p];
            float t0 = tb.x - M2, t1 = tb.y - M2;
            union { h16x2 pp; unsigned ii; } k1, k2;
            k1.pp = __builtin_amdgcn_cvt_pkrtz(exp2f(t0), exp2f(t1));
            k2.pp = __builtin_amdgcn_cvt_pkrtz(exp2f(NSL * t0), exp2f(NSL * t1));
            bvlds[p] = k1.ii;
            bwlds[p] = k2.ii;
        }
    }

    // ---- per-row A factors (two row sets: i0+l31 and i0+32+l31) ----
    float avL = a2[h * 4096 + i];
    float avH = a2[h * 4096 + i + 32];
    float uuL = avL + M2, uuH = avH + M2;
    float mvL = fmaxf(uuL, NSL * uuL);
    float mvH = fmaxf(uuH, NSL * uuH);
    union { h16x2 pp; f16x2v v; } apL, apH;
    apL.pp = __builtin_amdgcn_cvt_pkrtz(exp2f(uuL - mvL), exp2f(NSL * uuL - mvL));
    apH.pp = __builtin_amdgcn_cvt_pkrtz(exp2f(uuH - mvH), exp2f(NSL * uuH - mvH));
    f16x2v ApL1 = {apL.v.x, apL.v.x};
    f16x2v ApL2 = {apL.v.y, apL.v.y};
    f16x2v ApH1 = {apH.v.x, apH.v.x};
    f16x2v ApH2 = {apH.v.y, apH.v.y};

    f32x16 accL0 = {}, accL1 = {}, accL2 = {}, accL3 = {};
    f32x16 accH0 = {}, accH1 = {}, accH2 = {}, accH3 = {};
    float dsumL = 0.f, dsumH = 0.f;

    int J0 = w * 1024;
    const f16* bb = hbT2 + (size_t)h * 524288 + ((size_t)(J0 >> 4) * 128 + l31) * 16 + half * 8;
    const unsigned int* bpv = bvlds + (J0 >> 1) + half * 4;
    const unsigned int* bpw = bwlds + (J0 >> 1) + half * 4;
    // mask: word for row i, tile-pair tp is maskJ[((J0>>5)+tp)*4096 + i]; H row at +32 dwords
    const unsigned int* mp = maskJ + (size_t)(J0 >> 5) * 4096 + i;

    int sh0 = half << 3;
    int sh1 = 16 + (half << 3);

    __syncthreads();

    // prologue
    f16x8 fa0 = *(const f16x8*)(bb);
    f16x8 fa1 = *(const f16x8*)(bb + 512);
    f16x8 fa2 = *(const f16x8*)(bb + 1024);
    f16x8 fa3 = *(const f16x8*)(bb + 1536);
    int4 qv0 = ((const int4*)(bpv))[0];
    int4 qw0 = ((const int4*)(bpw))[0];
    unsigned mwcL = mp[0];
    unsigned mwcH = mp[32];
    mp += 4096;

    for (int tp = 0; tp < 32; tp++) {
        int t0 = tp * 2;
        const f16* s1 = bb + (size_t)(t0 + 1) * 2048;
        f16x8 fb0 = *(const f16x8*)(s1);
        f16x8 fb1 = *(const f16x8*)(s1 + 512);
        f16x8 fb2 = *(const f16x8*)(s1 + 1024);
        f16x8 fb3 = *(const f16x8*)(s1 + 1536);
        int4 qv1 = *(const int4*)(bpv + (t0 + 1) * 8);
        int4 qw1 = *(const int4*)(bpw + (t0 + 1) * 8);
        unsigned mwnL = mp[0];      // prefetch next tile-pair's mask words (L2, 1-tp distance)
        unsigned mwnH = mp[32];
        mp += 4096;

        {
            union { f16x8 v; unsigned u[4]; } af;
            PGEN2(af, mwcL >> sh0, qv0, qw0, ApL1, ApL2, dsumL);
            __builtin_amdgcn_s_setprio(1);
            accL0 = __builtin_amdgcn_mfma_f32_32x32x16_f16(af.v, fa0, accL0, 0, 0, 0);
            accL1 = __builtin_amdgcn_mfma_f32_32x32x16_f16(af.v, fa1, accL1, 0, 0, 0);
            accL2 = __builtin_amdgcn_mfma_f32_32x32x16_f16(af.v, fa2, accL2, 0, 0, 0);
            accL3 = __builtin_amdgcn_mfma_f32_32x32x16_f16(af.v, fa3, accL3, 0, 0, 0);
            __builtin_amdgcn_s_setprio(0);
        }
        {
            union { f16x8 v; unsigned u[4]; } af;
            PGEN2(af, mwcH >> sh0, qv0, qw0, ApH1, ApH2, dsumH);
            __builtin_amdgcn_s_setprio(1);
            accH0 = __builtin_amdgcn_mfma_f32_32x32x16_f16(af.v, fa0, accH0, 0, 0, 0);
            accH1 = __builtin_amdgcn_mfma_f32_32x32x16_f16(af.v, fa1, accH1, 0, 0, 0);
            accH2 = __builtin_amdgcn_mfma_f32_32x32x16_f16(af.v, fa2, accH2, 0, 0, 0);
            accH3 = __builtin_amdgcn_mfma_f32_32x32x16_f16(af.v, fa3, accH3, 0, 0, 0);
            __builtin_amdgcn_s_setprio(0);
        }

        const f16* s2 = bb + (size_t)(t0 + 2) * 2048;
        fa0 = *(const f16x8*)(s2);
        fa1 = *(const f16x8*)(s2 + 512);
        fa2 = *(const f16x8*)(s2 + 1024);
        fa3 = *(const f16x8*)(s2 + 1536);
        qv0 = *(const int4*)(bpv + (t0 + 2) * 8);
        qw0 = *(const int4*)(bpw + (t0 + 2) * 8);

        {
            union { f16x8 v; unsigned u[4]; } af;
            PGEN2(af, mwcL >> sh1, qv1, qw1, ApL1, ApL2, dsumL);
            __builtin_amdgcn_s_setprio(1);
            accL0 = __builtin_amdgcn_mfma_f32_32x32x16_f16(af.v, fb0, accL0, 0, 0, 0);
            accL1 = __builtin_amdgcn_mfma_f32_32x32x16_f16(af.v, fb1, accL1, 0, 0, 0);
            accL2 = __builtin_amdgcn_mfma_f32_32x32x16_f16(af.v, fb2, accL2, 0, 0, 0);
            accL3 = __builtin_amdgcn_mfma_f32_32x32x16_f16(af.v, fb3, accL3, 0, 0, 0);
            __builtin_amdgcn_s_setprio(0);
        }
        {
            union { f16x8 v; unsigned u[4]; } af;
            PGEN2(af, mwcH >> sh1, qv1, qw1, ApH1, ApH2, dsumH);
            __builtin_amdgcn_s_setprio(1);
            accH0 = __builtin_amdgcn_mfma_f32_32x32x16_f16(af.v, fb0, accH0, 0, 0, 0);
            accH1 = __builtin_amdgcn_mfma_f32_32x32x16_f16(af.v, fb1, accH1, 0, 0, 0);
            accH2 = __builtin_amdgcn_mfma_f32_32x32x16_f16(af.v, fb2, accH2, 0, 0, 0);
            accH3 = __builtin_amdgcn_mfma_f32_32x32x16_f16(af.v, fb3, accH3, 0, 0, 0);
            __builtin_amdgcn_s_setprio(0);
        }
        mwcL = mwnL;
        mwcH = mwnH;
    }

    // ---- denominator ----
    dsumL += __shfl(dsumL, lane ^ 32);
    dsumH += __shfl(dsumH, lane ^ 32);
    if (lane < 32) {
        dred[w * 64 + l31] = dsumL;
        dred[w * 64 + 32 + l31] = dsumH;
    }
    __syncthreads();
    {
        #pragma unroll
        for (int r = 0; r < 16; r++) {
            int row = (r & 3) + 8 * (r >> 2) + 4 * half;
            float sL = dred[row] + dred[64 + row] + dred[128 + row] + dred[192 + row];
            float sH = dred[32 + row] + dred[96 + row] + dred[160 + row] + dred[224 + row];
            float invL = 1.0f / sL;
            float invH = 1.0f / sH;
            accL0[r] *= invL; accL1[r] *= invL; accL2[r] *= invL; accL3[r] *= invL;
            accH0[r] *= invH; accH1[r] *= invH; accH2[r] *= invH; accH3[r] *= invH;
        }
    }

    // ---- residual (per-wave partial over K/4, summed in cross-wave reduction) ----
    {
        #pragma unroll
        for (int kt = 0; kt < 8; kt++) {
            int ktt = w * 8 + kt;
            f16x8 axL = *(const f16x8*)(xh2 + ((size_t)ktt * 4096 + i) * 16 + half * 8);
            f16x8 axH = *(const f16x8*)(xh2 + ((size_t)ktt * 4096 + i + 32) * 16 + half * 8);
            const f16* wb = Wrt2 + ((size_t)ktt * 1024 + h * 128 + l31) * 16 + half * 8;
            f16x8 wb0 = *(const f16x8*)(wb);
            f16x8 wb1 = *(const f16x8*)(wb + 512);
            f16x8 wb2 = *(const f16x8*)(wb + 1024);
            f16x8 wb3 = *(const f16x8*)(wb + 1536);
            accL0 = __builtin_amdgcn_mfma_f32_32x32x16_f16(axL, wb0, accL0, 0, 0, 0);
            accL1 = __builtin_amdgcn_mfma_f32_32x32x16_f16(axL, wb1, accL1, 0, 0, 0);
            accL2 = __builtin_amdgcn_mfma_f32_32x32x16_f16(axL, wb2, accL2, 0, 0, 0);
            accL3 = __builtin_amdgcn_mfma_f32_32x32x16_f16(axL, wb3, accL3, 0, 0, 0);
            accH0 = __builtin_amdgcn_mfma_f32_32x32x16_f16(axH, wb0, accH0, 0, 0, 0);
            accH1 = __builtin_amdgcn_mfma_f32_32x32x16_f16(axH, wb1, accH1, 0, 0, 0);
            accH2 = __builtin_amdgcn_mfma_f32_32x32x16_f16(axH, wb2, accH2, 0, 0, 0);
            accH3 = __builtin_amdgcn_mfma_f32_32x32x16_f16(axH, wb3, accH3, 0, 0, 0);
        }
    }

    // ---- cross-wave O reduction: pass L (rows i0..i0+31), then pass H (+32) ----
    float* xredb = (float*)smem;

    // pass L
    __syncthreads();
    if (w >= 2) {
        float* dp = xredb + (w - 2) * 4352 + lane * 68;
        PUTACC(dp, 0, accL0); PUTACC(dp, 16, accL1); PUTACC(dp, 32, accL2); PUTACC(dp, 48, accL3);
    }
    __syncthreads();
    if (w < 2) {
        const float* dp = xredb + w * 4352 + lane * 68;
        ADDACC(dp, 0, accL0); ADDACC(dp, 16, accL1); ADDACC(dp, 32, accL2); ADDACC(dp, 48, accL3);
    }
    __syncthreads();
    if (w == 1) {
        float* dp = xredb + lane * 68;
        PUTACC(dp, 0, accL0); PUTACC(dp, 16, accL1); PUTACC(dp, 32, accL2); PUTACC(dp, 48, accL3);
    }
    __syncthreads();
    if (w == 0) {
        const float* dp = xredb + lane * 68;
        ADDACC(dp, 0, accL0); ADDACC(dp, 16, accL1); ADDACC(dp, 32, accL2); ADDACC(dp, 48, accL3);
        #pragma unroll
        for (int n = 0; n < 4; n++) {
            union { f32x16 v; f32x4 q[4]; } t;
            t.v = (n == 0) ? accL0 : (n == 1) ? accL1 : (n == 2) ? accL2 : accL3;
            int col = h * 128 + n * 32 + l31;
            float bv = bias[col];
            #pragma unroll
            for (int r = 0; r < 16; r++) {
                int row = i0 + (r & 3) + 8 * (r >> 2) + 4 * half;
                out[(size_t)row * 1024 + col] = t.v[r] + bv;
            }
        }
    }

    // pass H
    __syncthreads();
    if (w >= 2) {
        float* dp = xredb + (w - 2) * 4352 + lane * 68;
        PUTACC(dp, 0, accH0); PUTACC(dp, 16, accH1); PUTACC(dp, 32, accH2); PUTACC(dp, 48, accH3);
    }
    __syncthreads();
    if (w < 2) {
        const float* dp = xredb + w * 4352 + lane * 68;
        ADDACC(dp, 0, accH0); ADDACC(dp, 16, accH1); ADDACC(dp, 32, accH2); ADDACC(dp, 48, accH3);
    }
    __syncthreads();
    if (w == 1) {
        float* dp = xredb + lane * 68;
        PUTACC(dp, 0, accH0); PUTACC(dp, 16, accH1); PUTACC(dp, 32, accH2); PUTACC(dp, 48, accH3);
    }
    __syncthreads();
    if (w == 0) {
        const float* dp = xredb + lane * 68;
        ADDACC(dp, 0, accH0); ADDACC(dp, 16, accH1); ADDACC(dp, 32, accH2); ADDACC(dp, 48, accH3);
        #pragma unroll
        for (int n = 0; n < 4; n++) {
            union { f32x16 v; f32x4 q[4]; } t;
            t.v = (n == 0) ? accH0 : (n == 1) ? accH1 : (n == 2) ? accH2 : accH3;
            int col = h * 128 + n * 32 + l31;
            float bv = bias[col];
            #pragma unroll
            for (int r = 0; r < 16; r++) {
                int row = i0 + 32 + (r & 3) + 8 * (r >> 2) + 4 * half;
                out[(size_t)row * 1024 + col] = t.v[r] + bv;
            }
        }
    }
}

extern "C" void kernel_launch(void* const* d_in, const int* in_sizes, int n_in,
                              void* d_out, int out_size, void* d_ws, size_t ws_size,
                              hipStream_t stream) {
    (void)in_sizes; (void)n_in; (void)out_size; (void)ws_size;
    const float* x     = (const float*)d_in[0];
    const int*   graph = (const int*)d_in[1];
    const float* W     = (const float*)d_in[2];
    const float* wi    = (const float*)d_in[3];
    const float* wj    = (const float*)d_in[4];
    const float* Wr    = (const float*)d_in[5];
    const float* bias  = (const float*)d_in[6];
    float* out = (float*)d_out;

    char* ws = (char*)d_ws;
    unsigned int* maskJ = (unsigned int*)ws;              // 2 MB  [128 jw][4096 i]
    f16* hbT2  = (f16*)(ws + (2u << 20));                 // 8 MB  [8][(j>>4)*128+f][j&15]
    f16* Wht2  = (f16*)(ws + (10u << 20));                // 1 MB  swizzled
    f16* Wrt2  = (f16*)(ws + (11u << 20));                // 1 MB  swizzled
    f16* xh2   = (f16*)(ws + (12u << 20));                // 4 MB  [32][4096][16] swizzled
    float* a2    = (float*)(ws + (16u << 20));            // 128 KB
    float* b2    = a2 + 8 * 4096;                         // 128 KB
    unsigned int* M2e = (unsigned int*)(b2 + 8 * 4096);   // 32 B

    hipLaunchKernelGGL(k_a, dim3(1536), dim3(256), 0, stream, x, xh2, W, Wht2, Wr, Wrt2, M2e);
    hipLaunchKernelGGL(k_b, dim3(3072), dim3(256), 0, stream, xh2, Wht2, hbT2,
                       wi, wj, a2, b2, M2e, graph, maskJ);
    hipLaunchKernelGGL(k_main, dim3(512), dim3(256), 0, stream, xh2, hbT2, Wrt2, maskJ,
                       a2, b2, M2e, bias, out);
}